// Round 5
// baseline (261.442 us; speedup 1.0000x reference)
//
#include <hip/hip_runtime.h>

// ROIAlign (FPN multi-level) for MI355X — R10: DECOMPOSITION ROUND.
//
// Kernel body is byte-equivalent to R8 (best fine-grained structure,
// 217.2us ~= R5's 216.5 within noise). The ONLY change: kernel_launch
// enqueues the SAME kernel 3x back-to-back. Output is written identically
// each time -> passed/absmax unchanged.
//
// Purpose: dur_us has never isolated the kernel's own dispatch time (the
// rocprof top-5 cutoff hides it behind 79-81us harness fills). With 3
// launches: dur_us(R10) - 217 = 2 x T_warm(kernel).
//   - ~300-330us -> T_warm ~55us: kernel time is structural (persists with
//     warm caches); attack request-volume / miss-queue next.
//   - ~235-250us -> T_warm ~10-15us: cold-HBM pass dominates; attack
//     unique-traffic/locality next.
//   - ~221-228us -> T_warm <5us: kernel is at the harness floor; declare.

#define B_SZ   2
#define N_ROI  512
#define CCH    256
#define OUT_S  7
#define NCELL  (OUT_S * OUT_S)
#define PAIRS  25                      // ceil(49 / 2)

typedef float nfloat4 __attribute__((ext_vector_type(4)));

__global__ __launch_bounds__(128)
void roialign_kernel(const float* __restrict__ fm2,
                     const float* __restrict__ fm3,
                     const float* __restrict__ fm4,
                     const float* __restrict__ fm5,
                     const float* __restrict__ rois,
                     float* __restrict__ out)
{
    // decode swizzled block id -> (roi, cell pair); wave id -> which cell
    const int bidx = blockIdx.x;
    const int g    = bidx & 7;            // XCD slot == roi & 7
    const int q    = bidx >> 3;           // 0 .. 3199
    const int rhi  = q / PAIRS;           // 0 .. 127  (roi >> 3)
    const int p    = q - rhi * PAIRS;     // pair 0..24
    const int bn   = (rhi << 3) | g;      // ROI id 0..1023
    const int w_id = threadIdx.x >> 6;    // wave 0/1
    const int cell = 2 * p + w_id;        // 0..49
    if (cell >= NCELL) return;            // pad wave (no barriers -> safe)
    const int jy   = cell / OUT_S;        // row 0..6
    const int ix   = cell - jy * OUT_S;   // col 0..6
    const int b    = bn >> 9;             // batch (N=512)

    // ---- per-ROI setup (wave-uniform) ----
    const float4 roi = ((const float4*)rois)[bn];   // x1,y1,x2,y2
    const float x1 = roi.x, y1 = roi.y;
    const float w  = roi.z - roi.x;
    const float h  = roi.w - roi.y;

    float lvf = log2f(sqrtf(w * h) * (1.0f / 224.0f)) + 4.0f;
    int lv = (int)rintf(lvf);                   // RNE, matches jnp.round
    lv = min(max(lv, 2), 5) - 2;                // 0..3

    const float* fm = (lv == 0) ? fm2 : (lv == 1) ? fm3 : (lv == 2) ? fm4 : fm5;
    const int    H      = 256 >> lv;            // H == W
    const float  stride = (float)(4 << lv);
    const float  scale  = (float)(H - 1) / (stride * (float)H);

    // ---- sample coordinate for this (row, col) cell ----
    const float gy = (float)jy * (1.0f / 6.0f);
    const float gx = (float)ix * (1.0f / 6.0f);
    const float cy = (y1 + gy * h) * scale;     // ref: ((y1+g*h)/stride/H)*(H-1)
    const float cx = (x1 + gx * w) * scale;

    const int vld = (cy >= 0.0f) & (cy <= (float)(H - 1)) &
                    (cx >= 0.0f) & (cx <= (float)(H - 1));

    const float cyc = fminf(fmaxf(cy, 0.0f), (float)(H - 1));
    const float cxc = fminf(fmaxf(cx, 0.0f), (float)(H - 1));
    const int   y0  = (int)floorf(cyc);
    const int   x0  = (int)floorf(cxc);
    const float yl  = cyc - (float)y0;
    const float xl  = cxc - (float)x0;
    const int   y1i = min(y0 + 1, H - 1);
    const int   x1i = min(x0 + 1, H - 1);

    // ---- gather + bilinear: lane handles 4 channels (float4) ----
    const int c = (threadIdx.x & 63) * 4;

    const float* base = fm + (size_t)b * (size_t)H * (size_t)H * CCH;
    const float* rowT = base + (size_t)y0  * H * CCH;
    const float* rowB = base + (size_t)y1i * H * CCH;

    const float4 tl = *(const float4*)(rowT + x0  * CCH + c);
    const float4 tr = *(const float4*)(rowT + x1i * CCH + c);
    const float4 bl = *(const float4*)(rowB + x0  * CCH + c);
    const float4 br = *(const float4*)(rowB + x1i * CCH + c);

    nfloat4 o;
    {
        const float tx = tl.x + (tr.x - tl.x) * xl;
        const float bx = bl.x + (br.x - bl.x) * xl;
        o.x = tx + (bx - tx) * yl;
    }
    {
        const float ty = tl.y + (tr.y - tl.y) * xl;
        const float by = bl.y + (br.y - bl.y) * xl;
        o.y = ty + (by - ty) * yl;
    }
    {
        const float tz = tl.z + (tr.z - tl.z) * xl;
        const float bz = bl.z + (br.z - bl.z) * xl;
        o.z = tz + (bz - tz) * yl;
    }
    {
        const float tw = tl.w + (tr.w - tl.w) * xl;
        const float bw = bl.w + (br.w - bl.w) * xl;
        o.w = tw + (bw - tw) * yl;
    }
    if (!vld) { o.x = 0.0f; o.y = 0.0f; o.z = 0.0f; o.w = 0.0f; }

    // write-once output: non-temporal to keep it out of L2
    nfloat4* dst = (nfloat4*)(out + (size_t)bn * NCELL * CCH
                                  + (size_t)cell * CCH + c);
    __builtin_nontemporal_store(o, dst);
}

extern "C" void kernel_launch(void* const* d_in, const int* in_sizes, int n_in,
                              void* d_out, int out_size, void* d_ws, size_t ws_size,
                              hipStream_t stream) {
    const float* fm2  = (const float*)d_in[0];
    const float* fm3  = (const float*)d_in[1];
    const float* fm4  = (const float*)d_in[2];
    const float* fm5  = (const float*)d_in[3];
    const float* rois = (const float*)d_in[4];
    float* out = (float*)d_out;

    dim3 grid(8 * (N_ROI * B_SZ / 8) * PAIRS);   // 25600 blocks (XCD-swizzled)
    dim3 block(128);                             // 2 waves = 2 cells

    // 3 identical launches: #1 = normal (cold), #2/#3 = fully warm.
    // dur_us - 217 ~= 2 x T_warm. Output idempotent.
    hipLaunchKernelGGL(roialign_kernel, grid, block, 0, stream,
                       fm2, fm3, fm4, fm5, rois, out);
    hipLaunchKernelGGL(roialign_kernel, grid, block, 0, stream,
                       fm2, fm3, fm4, fm5, rois, out);
    hipLaunchKernelGGL(roialign_kernel, grid, block, 0, stream,
                       fm2, fm3, fm4, fm5, rois, out);
}

// Round 6
// 222.505 us; speedup vs baseline: 1.1750x; 1.1750x over previous
//
#include <hip/hip_runtime.h>

// ROIAlign (FPN multi-level) for MI355X — R11: cache self-warming.
//
// Gather structure = R8 verbatim (best, 217.2us; occupancy/MLP/granularity
// all measured neutral). R10's 3-launch decomposition: T_warm ~= 22us,
// T_cold ~= 55us -> ~33us/rep is cold-cache penalty (harness's 2x512MiB
// poison fills flush L3 every rep). Model: ~250MB of corner-load request
// traffic is slot-limited in the per-CU miss queue; time ~= lines/slots x
// avg_latency. Volume & slots are fixed (FPN level normalization makes the
// 196 corner-loads/ROI ~unique pixels -> no sharing), so the lever is
// LATENCY: first-resident 4096 blocks stream fm3+fm4+fm5 (44MB, the whole
// hot footprint; fm2's 134MB serves ~3% of ROIs, skipped) with coalesced
// float4 loads -> L2/L3 resident in ~7us -> gather misses become ~200-300cy
// L2/L3 hits instead of 600-900cy HBM.
//  - no barrier needed: gathers racing ahead of the prefetch are slower,
//    never wrong. Prefetch blocks span all XCD slots (bidx&7 uniform).
//  - anti-DCE: asm volatile keep-alive on the prefetched values.
// Exact per-lane counts: fm3 = 2,097,152 float4 = 4/lane; fm4 = 524,288
// = 1/lane; fm5 = 131,072 = 1/lane for lane_id < 131072. (4096 blk x 128)

#define B_SZ   2
#define N_ROI  512
#define CCH    256
#define OUT_S  7
#define NCELL  (OUT_S * OUT_S)
#define PAIRS  25                      // ceil(49 / 2)
#define PF_BLOCKS 4096                 // first-resident set: 256 CU x 16 wg

typedef float nfloat4 __attribute__((ext_vector_type(4)));

__global__ __launch_bounds__(128)
void roialign_kernel(const float* __restrict__ fm2,
                     const float* __restrict__ fm3,
                     const float* __restrict__ fm4,
                     const float* __restrict__ fm5,
                     const float* __restrict__ rois,
                     float* __restrict__ out)
{
    const int bidx = blockIdx.x;

    // ---- phase 0: cache self-warming (first-resident blocks only) ----
    if (bidx < PF_BLOCKS) {
        const int lane_id = bidx * 128 + (int)threadIdx.x;   // 0 .. 524287
        const float4* f3 = (const float4*)fm3;
        const float4* f4 = (const float4*)fm4;
        const float4* f5 = (const float4*)fm5;
        float4 a0 = f3[lane_id];
        float4 a1 = f3[lane_id +  524288];
        float4 a2 = f3[lane_id + 1048576];
        float4 a3 = f3[lane_id + 1572864];
        float4 a4 = f4[lane_id];
        float4 a5 = (lane_id < 131072) ? f5[lane_id] : a0;
        // keep loads live without using them (rule: ablation-via-skip DCEs)
        asm volatile("" :: "v"(a0.x), "v"(a1.x), "v"(a2.x),
                           "v"(a3.x), "v"(a4.x), "v"(a5.x));
    }

    // ---- gather (R8 structure, unchanged) ----
    const int g    = bidx & 7;            // XCD slot == roi & 7
    const int q    = bidx >> 3;           // 0 .. 3199
    const int rhi  = q / PAIRS;           // 0 .. 127  (roi >> 3)
    const int p    = q - rhi * PAIRS;     // pair 0..24
    const int bn   = (rhi << 3) | g;      // ROI id 0..1023
    const int w_id = threadIdx.x >> 6;    // wave 0/1
    const int cell = 2 * p + w_id;        // 0..49
    if (cell >= NCELL) return;            // pad wave (no barriers -> safe)
    const int jy   = cell / OUT_S;        // row 0..6
    const int ix   = cell - jy * OUT_S;   // col 0..6
    const int b    = bn >> 9;             // batch (N=512)

    // ---- per-ROI setup (wave-uniform) ----
    const float4 roi = ((const float4*)rois)[bn];   // x1,y1,x2,y2
    const float x1 = roi.x, y1 = roi.y;
    const float w  = roi.z - roi.x;
    const float h  = roi.w - roi.y;

    float lvf = log2f(sqrtf(w * h) * (1.0f / 224.0f)) + 4.0f;
    int lv = (int)rintf(lvf);                   // RNE, matches jnp.round
    lv = min(max(lv, 2), 5) - 2;                // 0..3

    const float* fm = (lv == 0) ? fm2 : (lv == 1) ? fm3 : (lv == 2) ? fm4 : fm5;
    const int    H      = 256 >> lv;            // H == W
    const float  stride = (float)(4 << lv);
    const float  scale  = (float)(H - 1) / (stride * (float)H);

    // ---- sample coordinate for this (row, col) cell ----
    const float gy = (float)jy * (1.0f / 6.0f);
    const float gx = (float)ix * (1.0f / 6.0f);
    const float cy = (y1 + gy * h) * scale;     // ref: ((y1+g*h)/stride/H)*(H-1)
    const float cx = (x1 + gx * w) * scale;

    const int vld = (cy >= 0.0f) & (cy <= (float)(H - 1)) &
                    (cx >= 0.0f) & (cx <= (float)(H - 1));

    const float cyc = fminf(fmaxf(cy, 0.0f), (float)(H - 1));
    const float cxc = fminf(fmaxf(cx, 0.0f), (float)(H - 1));
    const int   y0  = (int)floorf(cyc);
    const int   x0  = (int)floorf(cxc);
    const float yl  = cyc - (float)y0;
    const float xl  = cxc - (float)x0;
    const int   y1i = min(y0 + 1, H - 1);
    const int   x1i = min(x0 + 1, H - 1);

    // ---- gather + bilinear: lane handles 4 channels (float4) ----
    const int c = (threadIdx.x & 63) * 4;

    const float* base = fm + (size_t)b * (size_t)H * (size_t)H * CCH;
    const float* rowT = base + (size_t)y0  * H * CCH;
    const float* rowB = base + (size_t)y1i * H * CCH;

    const float4 tl = *(const float4*)(rowT + x0  * CCH + c);
    const float4 tr = *(const float4*)(rowT + x1i * CCH + c);
    const float4 bl = *(const float4*)(rowB + x0  * CCH + c);
    const float4 br = *(const float4*)(rowB + x1i * CCH + c);

    nfloat4 o;
    {
        const float tx = tl.x + (tr.x - tl.x) * xl;
        const float bx = bl.x + (br.x - bl.x) * xl;
        o.x = tx + (bx - tx) * yl;
    }
    {
        const float ty = tl.y + (tr.y - tl.y) * xl;
        const float by = bl.y + (br.y - bl.y) * xl;
        o.y = ty + (by - ty) * yl;
    }
    {
        const float tz = tl.z + (tr.z - tl.z) * xl;
        const float bz = bl.z + (br.z - bl.z) * xl;
        o.z = tz + (bz - tz) * yl;
    }
    {
        const float tw = tl.w + (tr.w - tl.w) * xl;
        const float bw = bl.w + (br.w - bl.w) * xl;
        o.w = tw + (bw - tw) * yl;
    }
    if (!vld) { o.x = 0.0f; o.y = 0.0f; o.z = 0.0f; o.w = 0.0f; }

    // write-once output: non-temporal to keep it out of L2
    nfloat4* dst = (nfloat4*)(out + (size_t)bn * NCELL * CCH
                                  + (size_t)cell * CCH + c);
    __builtin_nontemporal_store(o, dst);
}

extern "C" void kernel_launch(void* const* d_in, const int* in_sizes, int n_in,
                              void* d_out, int out_size, void* d_ws, size_t ws_size,
                              hipStream_t stream) {
    const float* fm2  = (const float*)d_in[0];
    const float* fm3  = (const float*)d_in[1];
    const float* fm4  = (const float*)d_in[2];
    const float* fm5  = (const float*)d_in[3];
    const float* rois = (const float*)d_in[4];
    float* out = (float*)d_out;

    dim3 grid(8 * (N_ROI * B_SZ / 8) * PAIRS);   // 25600 blocks (XCD-swizzled)
    dim3 block(128);                             // 2 waves = 2 cells
    hipLaunchKernelGGL(roialign_kernel, grid, block, 0, stream,
                       fm2, fm3, fm4, fm5, rois, out);
}